// Round 1
// baseline (107.384 us; speedup 1.0000x reference)
//
#include <hip/hip_runtime.h>
#include <hip/hip_bf16.h>
#include <stdint.h>

// Problem shapes (fixed by setup_inputs)
#define BB 8
#define NN 4096
#define FF 2048
#define EE 128

typedef __attribute__((ext_vector_type(8))) short short8;
typedef __attribute__((ext_vector_type(4))) float floatx4;

__device__ __forceinline__ unsigned short f2bf(float x) {
    union { float f; uint32_t u; } v; v.f = x;
    uint32_t u = v.u;
    uint32_t r = (u + 0x7FFFu + ((u >> 16) & 1u)) >> 16;
    return (unsigned short)r;
}

__device__ __forceinline__ float wred_sum(float v) {
    #pragma unroll
    for (int o = 32; o; o >>= 1) v += __shfl_xor(v, o, 64);
    return v;
}

// ---------------------------------------------------------------------------
// Kernel 1: per (b,f): C_sp = d_rel + d_a1 + ||f3||^2 ; C_po = d_rel + d_a2 + ||f2||^2
// (invalid facts -> +1e30). Also emit fact2/fact3 as bf16, XOR-swizzled per row
// (16B slot j -> j ^ (f&7)) so the main kernel stages linearly and reads b128
// conflict-free.
// ---------------------------------------------------------------------------
__global__ __launch_bounds__(256) void prep_facts(
    const float* __restrict__ rel, const float* __restrict__ arg1,
    const float* __restrict__ arg2, const float* __restrict__ f1,
    const float* __restrict__ f2, const float* __restrict__ f3,
    const int* __restrict__ nbf,
    unsigned short* __restrict__ f2b, unsigned short* __restrict__ f3b,
    float* __restrict__ Csp, float* __restrict__ Cpo)
{
    int gid  = blockIdx.x * 4 + (threadIdx.x >> 6);   // wave id over B*F
    int lane = threadIdx.x & 63;
    int b = gid >> 11;           // F = 2048
    int f = gid & (FF - 1);

    const float2* rp  = (const float2*)(rel  + (size_t)b * EE);
    const float2* a1p = (const float2*)(arg1 + (size_t)b * EE);
    const float2* a2p = (const float2*)(arg2 + (size_t)b * EE);
    const float2* p1  = (const float2*)(f1 + (size_t)gid * EE);
    const float2* p2  = (const float2*)(f2 + (size_t)gid * EE);
    const float2* p3  = (const float2*)(f3 + (size_t)gid * EE);

    float2 vr = rp[lane], va1 = a1p[lane], va2 = a2p[lane];
    float2 v1 = p1[lane], v2 = p2[lane], v3 = p3[lane];

    float dx, dy;
    dx = vr.x - v1.x;  dy = vr.y - v1.y;  float dr  = dx*dx + dy*dy;
    dx = va1.x - v2.x; dy = va1.y - v2.y; float da1 = dx*dx + dy*dy;
    dx = va2.x - v3.x; dy = va2.y - v3.y; float da2 = dx*dx + dy*dy;
    float s2 = v2.x*v2.x + v2.y*v2.y;
    float s3 = v3.x*v3.x + v3.y*v3.y;

    // bf16 swizzled store: lane covers byte range [lane*4, lane*4+4) of the 256B row
    int slot = lane >> 2;                 // 16B slot index (0..15)
    int swz  = slot ^ (f & 7);
    size_t dbyte = (size_t)gid * 256 + (size_t)(swz << 4) + ((lane & 3) << 2);
    uint32_t pk2 = (uint32_t)f2bf(v2.x) | ((uint32_t)f2bf(v2.y) << 16);
    uint32_t pk3 = (uint32_t)f2bf(v3.x) | ((uint32_t)f2bf(v3.y) << 16);
    *(uint32_t*)((char*)f2b + dbyte) = pk2;
    *(uint32_t*)((char*)f3b + dbyte) = pk3;

    dr = wred_sum(dr); da1 = wred_sum(da1); da2 = wred_sum(da2);
    s2 = wred_sum(s2); s3 = wred_sum(s3);

    if (lane == 0) {
        bool fv = f < nbf[b];
        Csp[gid] = fv ? (dr + da1 + s3) : 1e30f;
        Cpo[gid] = fv ? (dr + da2 + s2) : 1e30f;
    }
}

// ---------------------------------------------------------------------------
// Kernel 2: per (b,n): ||ent||^2 (f32-exact) + bf16 ent row (linear layout).
// ---------------------------------------------------------------------------
__global__ __launch_bounds__(256) void prep_ent(
    const float* __restrict__ ent, unsigned short* __restrict__ entb,
    float* __restrict__ enorm)
{
    int gid  = blockIdx.x * 4 + (threadIdx.x >> 6);   // wave id over B*N
    int lane = threadIdx.x & 63;

    const float2* p = (const float2*)(ent + (size_t)gid * EE);
    float2 v = p[lane];
    uint32_t pk = (uint32_t)f2bf(v.x) | ((uint32_t)f2bf(v.y) << 16);
    *(uint32_t*)((char*)entb + (size_t)gid * 256 + (lane << 2)) = pk;

    float nrm = wred_sum(v.x*v.x + v.y*v.y);
    if (lane == 0) enorm[gid] = nrm;
}

// ---------------------------------------------------------------------------
// Kernel 3: main fused GEMM-min-exp.
// Grid 256 blocks, 256 threads (4 waves). b = blockIdx&7 (XCD/L2 affinity),
// 128 entities per block. Ent A-frags in registers; loop 16 f-tiles of 128:
// stage fact3+fact2 (64KB LDS) via global_load_lds(16B), 16x16x32 bf16 MFMA,
// fused epilogue min(C[f] - 2*cross) into registers. Final: shfl min, exp, mask.
// ---------------------------------------------------------------------------
__device__ __forceinline__ void gemm_min_tile(
    const unsigned short* lds, const float* __restrict__ cbase,
    const short8 (&a)[2][4], int l15, int kgrp, int lane, float (&rm)[2][4])
{
    floatx4 acc[2][8];
    #pragma unroll
    for (int i = 0; i < 2; ++i)
        #pragma unroll
        for (int fj = 0; fj < 8; ++fj)
            acc[i][fj] = floatx4{0.f, 0.f, 0.f, 0.f};

    #pragma unroll
    for (int kk = 0; kk < 4; ++kk) {
        short8 bf[8];
        int swb = ((kk * 4 + kgrp) ^ (lane & 7)) << 4;   // swizzled 16B slot byte
        #pragma unroll
        for (int fj = 0; fj < 8; ++fj) {
            int r = fj * 16 + l15;
            bf[fj] = *(const short8*)((const char*)lds + r * 256 + swb);
        }
        #pragma unroll
        for (int i = 0; i < 2; ++i)
            #pragma unroll
            for (int fj = 0; fj < 8; ++fj)
                acc[i][fj] = __builtin_amdgcn_mfma_f32_16x16x32_bf16(
                    a[i][kk], bf[fj], acc[i][fj], 0, 0, 0);
    }
    #pragma unroll
    for (int fj = 0; fj < 8; ++fj) {
        float c = cbase[fj * 16 + l15];
        #pragma unroll
        for (int i = 0; i < 2; ++i)
            #pragma unroll
            for (int r = 0; r < 4; ++r)
                rm[i][r] = fminf(rm[i][r], fmaf(-2.f, acc[i][fj][r], c));
    }
}

__global__ __launch_bounds__(256) void kb_main(
    const unsigned short* __restrict__ entb,
    const unsigned short* __restrict__ f2b,
    const unsigned short* __restrict__ f3b,
    const float* __restrict__ Csp, const float* __restrict__ Cpo,
    const float* __restrict__ enorm, const int* __restrict__ nbe,
    float* __restrict__ out)
{
    __shared__ unsigned short lds3[128 * 128];
    __shared__ unsigned short lds2[128 * 128];

    int b     = blockIdx.x & 7;
    int ntile = blockIdx.x >> 3;
    int nbase = ntile * 128;
    int tid = threadIdx.x, w = tid >> 6, lane = tid & 63;
    int l15 = lane & 15, kgrp = lane >> 4;

    // A-frags: ent rows for this wave (rows w*32 .. w*32+31), all K
    short8 a[2][4];
    {
        const unsigned short* pe = entb + ((size_t)b * NN + nbase) * EE;
        #pragma unroll
        for (int i = 0; i < 2; ++i) {
            const unsigned short* pr = pe + (size_t)(w * 32 + i * 16 + l15) * EE + kgrp * 8;
            #pragma unroll
            for (int kk = 0; kk < 4; ++kk)
                a[i][kk] = *(const short8*)(pr + kk * 32);
        }
    }

    float rmsp[2][4], rmpo[2][4];
    #pragma unroll
    for (int i = 0; i < 2; ++i)
        #pragma unroll
        for (int r = 0; r < 4; ++r) { rmsp[i][r] = 3.0e38f; rmpo[i][r] = 3.0e38f; }

    const char* src3 = (const char*)f3b + (size_t)b * FF * 256;
    const char* src2 = (const char*)f2b + (size_t)b * FF * 256;

    for (int ft = 0; ft < 16; ++ft) {
        // stage 32KB (fact3) + 32KB (fact2); each wave copies its 8KB quarter
        {
            int off = w * 8192;
            const char* g3 = src3 + (size_t)ft * 32768 + off + lane * 16;
            const char* g2 = src2 + (size_t)ft * 32768 + off + lane * 16;
            char* l3 = (char*)lds3 + off;
            char* l2 = (char*)lds2 + off;
            #pragma unroll
            for (int it = 0; it < 8; ++it) {
                __builtin_amdgcn_global_load_lds(
                    (const __attribute__((address_space(1))) void*)(g3 + it * 1024),
                    (__attribute__((address_space(3))) void*)(l3 + it * 1024), 16, 0, 0);
                __builtin_amdgcn_global_load_lds(
                    (const __attribute__((address_space(1))) void*)(g2 + it * 1024),
                    (__attribute__((address_space(3))) void*)(l2 + it * 1024), 16, 0, 0);
            }
        }
        __syncthreads();

        gemm_min_tile(lds3, Csp + b * FF + ft * 128, a, l15, kgrp, lane, rmsp);
        gemm_min_tile(lds2, Cpo + b * FF + ft * 128, a, l15, kgrp, lane, rmpo);

        __syncthreads();
    }

    // final: min across the 16 lanes sharing each output row, then exp + mask
    const float* enb = enorm + b * NN + nbase;
    int nbent = nbe[b];
    #pragma unroll
    for (int i = 0; i < 2; ++i)
        #pragma unroll
        for (int r = 0; r < 4; ++r) {
            float vs = rmsp[i][r], vp = rmpo[i][r];
            #pragma unroll
            for (int o = 1; o < 16; o <<= 1) {
                vs = fminf(vs, __shfl_xor(vs, o, 64));
                vp = fminf(vp, __shfl_xor(vp, o, 64));
            }
            if (l15 == 0) {
                int nl = w * 32 + i * 16 + kgrp * 4 + r;
                int n  = nbase + nl;
                bool valid = n < nbent;
                float no = enb[nl];
                out[(size_t)b * NN + n] = valid ? __expf(-0.5f * (vs + no)) : 0.f;
                out[(size_t)BB * NN + (size_t)b * NN + n] =
                    valid ? __expf(-0.5f * (vp + no)) : 0.f;
            }
        }
}

// ---------------------------------------------------------------------------
// Workspace layout (bytes):
//   [0,        4MB)  fact2 bf16 (swizzled)
//   [4MB,      8MB)  fact3 bf16 (swizzled)
//   [8MB,     16MB)  ent bf16 (linear)
//   [16MB,       +64KB)  C_sp
//   [16MB+64K,  +64KB)  C_po
//   [16MB+128K,+128KB)  ent_norm
// Total 16.25 MB.
// ---------------------------------------------------------------------------
extern "C" void kernel_launch(void* const* d_in, const int* in_sizes, int n_in,
                              void* d_out, int out_size, void* d_ws, size_t ws_size,
                              hipStream_t stream) {
    const float* rel  = (const float*)d_in[0];
    const float* arg1 = (const float*)d_in[1];
    const float* arg2 = (const float*)d_in[2];
    const float* f1   = (const float*)d_in[3];
    const float* f2   = (const float*)d_in[4];
    const float* f3   = (const float*)d_in[5];
    const float* ent  = (const float*)d_in[6];
    const int*   nbf  = (const int*)d_in[7];
    const int*   nbe  = (const int*)d_in[8];

    char* ws = (char*)d_ws;
    unsigned short* f2b  = (unsigned short*)(ws);
    unsigned short* f3b  = (unsigned short*)(ws + (4u << 20));
    unsigned short* entb = (unsigned short*)(ws + (8u << 20));
    float* Csp   = (float*)(ws + (16u << 20));
    float* Cpo   = (float*)(ws + (16u << 20) + 65536);
    float* enorm = (float*)(ws + (16u << 20) + 131072);
    float* out = (float*)d_out;

    hipLaunchKernelGGL(prep_facts, dim3(BB * FF / 4), dim3(256), 0, stream,
                       rel, arg1, arg2, f1, f2, f3, nbf, f2b, f3b, Csp, Cpo);
    hipLaunchKernelGGL(prep_ent, dim3(BB * NN / 4), dim3(256), 0, stream,
                       ent, entb, enorm);
    hipLaunchKernelGGL(kb_main, dim3(256), dim3(256), 0, stream,
                       entb, f2b, f3b, Csp, Cpo, enorm, nbe, out);
}

// Round 2
// 59.882 us; speedup vs baseline: 1.7933x; 1.7933x over previous
//
#include <hip/hip_runtime.h>
#include <stdint.h>

// Problem shapes (fixed by setup_inputs)
#define BB 8
#define NN 4096
#define FF 2048
#define EE 128

typedef __attribute__((ext_vector_type(8))) short short8;
typedef __attribute__((ext_vector_type(4))) float floatx4;

__device__ __forceinline__ unsigned short f2bf(float x) {
    union { float f; uint32_t u; } v; v.f = x;
    uint32_t u = v.u;
    return (unsigned short)((u + 0x7FFFu + ((u >> 16) & 1u)) >> 16);
}

__device__ __forceinline__ float wred_sum(float v) {
#pragma unroll
    for (int o = 32; o; o >>= 1) v += __shfl_xor(v, o, 64);
    return v;
}

#define NFB (BB * FF / 4)   // 4096 blocks for fact prep (4 waves each)
#define NEB (BB * NN / 4)   // 8192 blocks for entity prep

// ---------------------------------------------------------------------------
// Fused prep: fact branch computes C_sp/C_po + bf16 swizzled fact2/fact3;
// entity branch computes ||ent||^2 + bf16 linear ent rows.
// ---------------------------------------------------------------------------
__global__ __launch_bounds__(256) void prep_all(
    const float* __restrict__ rel, const float* __restrict__ arg1,
    const float* __restrict__ arg2, const float* __restrict__ f1,
    const float* __restrict__ f2, const float* __restrict__ f3,
    const float* __restrict__ ent, const int* __restrict__ nbf,
    unsigned short* __restrict__ f2b, unsigned short* __restrict__ f3b,
    unsigned short* __restrict__ entb,
    float* __restrict__ Csp, float* __restrict__ Cpo, float* __restrict__ enorm)
{
    int lane = threadIdx.x & 63;
    if (blockIdx.x < NFB) {
        int gid = blockIdx.x * 4 + (threadIdx.x >> 6);   // over B*F
        int b = gid >> 11;
        int f = gid & (FF - 1);

        const float2* rp  = (const float2*)(rel  + (size_t)b * EE);
        const float2* a1p = (const float2*)(arg1 + (size_t)b * EE);
        const float2* a2p = (const float2*)(arg2 + (size_t)b * EE);
        const float2* p1  = (const float2*)(f1 + (size_t)gid * EE);
        const float2* p2  = (const float2*)(f2 + (size_t)gid * EE);
        const float2* p3  = (const float2*)(f3 + (size_t)gid * EE);

        float2 vr = rp[lane], va1 = a1p[lane], va2 = a2p[lane];
        float2 v1 = p1[lane], v2 = p2[lane], v3 = p3[lane];

        float dx, dy;
        dx = vr.x - v1.x;  dy = vr.y - v1.y;  float dr  = dx*dx + dy*dy;
        dx = va1.x - v2.x; dy = va1.y - v2.y; float da1 = dx*dx + dy*dy;
        dx = va2.x - v3.x; dy = va2.y - v3.y; float da2 = dx*dx + dy*dy;
        float s2 = v2.x*v2.x + v2.y*v2.y;
        float s3 = v3.x*v3.x + v3.y*v3.y;

        // bf16 swizzled store: 16B slot j -> j ^ (f&7)
        int slot = lane >> 2;
        int swz  = slot ^ (f & 7);
        size_t dbyte = (size_t)gid * 256 + (size_t)(swz << 4) + ((lane & 3) << 2);
        uint32_t pk2 = (uint32_t)f2bf(v2.x) | ((uint32_t)f2bf(v2.y) << 16);
        uint32_t pk3 = (uint32_t)f2bf(v3.x) | ((uint32_t)f2bf(v3.y) << 16);
        *(uint32_t*)((char*)f2b + dbyte) = pk2;
        *(uint32_t*)((char*)f3b + dbyte) = pk3;

        dr = wred_sum(dr); da1 = wred_sum(da1); da2 = wred_sum(da2);
        s2 = wred_sum(s2); s3 = wred_sum(s3);

        if (lane == 0) {
            bool fv = f < nbf[b];
            Csp[gid] = fv ? (dr + da1 + s3) : 1e30f;
            Cpo[gid] = fv ? (dr + da2 + s2) : 1e30f;
        }
    } else {
        int gid = (blockIdx.x - NFB) * 4 + (threadIdx.x >> 6);   // over B*N
        const float2* p = (const float2*)(ent + (size_t)gid * EE);
        float2 v = p[lane];
        uint32_t pk = (uint32_t)f2bf(v.x) | ((uint32_t)f2bf(v.y) << 16);
        *(uint32_t*)((char*)entb + (size_t)gid * 256 + (lane << 2)) = pk;
        float nrm = wred_sum(v.x*v.x + v.y*v.y);
        if (lane == 0) enorm[gid] = nrm;
    }
}

// ---------------------------------------------------------------------------
// Main fused GEMM-min kernel.
// Grid 512 = b(8, low bits: XCD affinity) x ntile(32) x fsplit(2).
// Block 128 threads (2 waves); wave owns 64 entity rows (I=4 strips of 16).
// F-half = 1024 facts, tiles of 128; fact3/fact2 tiles alternate as a natural
// double buffer: stage next tile before computing current (2-phase pipeline).
// B-read:MFMA ratio = 1:4. Writes partial min-distances to pm.
// ---------------------------------------------------------------------------
__device__ __forceinline__ void stage_tile(const char* src, char* dst, int w, int lane) {
    const char* g = src + w * 16384 + lane * 16;
    char* l = dst + w * 16384 + lane * 16;
#pragma unroll
    for (int it = 0; it < 16; ++it)
        __builtin_amdgcn_global_load_lds(
            (const __attribute__((address_space(1))) void*)(g + it * 1024),
            (__attribute__((address_space(3))) void*)(l + it * 1024), 16, 0, 0);
}

__device__ __forceinline__ void compute_tile(
    const char* buf, const float* __restrict__ cvec,
    const short8 (&a)[4][4], int l15, int kgrp, int lane, float (&rm)[4][4])
{
#pragma unroll
    for (int fj = 0; fj < 8; ++fj) {
        int row = fj * 16 + l15;
        const char* rp = buf + row * 256;
        int sw = lane & 7;
        short8 bf[4];
#pragma unroll
        for (int kk = 0; kk < 4; ++kk)
            bf[kk] = *(const short8*)(rp + (((kk * 4 + kgrp) ^ sw) << 4));
        floatx4 acc[4];
#pragma unroll
        for (int i = 0; i < 4; ++i) acc[i] = floatx4{0.f, 0.f, 0.f, 0.f};
#pragma unroll
        for (int kk = 0; kk < 4; ++kk)
#pragma unroll
            for (int i = 0; i < 4; ++i)
                acc[i] = __builtin_amdgcn_mfma_f32_16x16x32_bf16(
                    a[i][kk], bf[kk], acc[i], 0, 0, 0);
        float c = cvec[fj * 16 + l15];
#pragma unroll
        for (int i = 0; i < 4; ++i)
#pragma unroll
            for (int r = 0; r < 4; ++r)
                rm[i][r] = fminf(rm[i][r], fmaf(-2.f, acc[i][r], c));
    }
}

__global__ __launch_bounds__(128) void kb_main(
    const unsigned short* __restrict__ entb,
    const unsigned short* __restrict__ f2b,
    const unsigned short* __restrict__ f3b,
    const float* __restrict__ Csp, const float* __restrict__ Cpo,
    float* __restrict__ pm)
{
    __shared__ char b3[32768];
    __shared__ char b2[32768];

    int bid = blockIdx.x;
    int b  = bid & 7;
    int nt = (bid >> 3) & 31;
    int fs = bid >> 8;
    int nbase = nt * 128;
    int fbase = fs * 1024;

    int tid = threadIdx.x, w = tid >> 6, lane = tid & 63;
    int l15 = lane & 15, kgrp = lane >> 4;

    // A-frags: ent rows nbase + w*64 + i*16 + l15, all K
    short8 a[4][4];
    {
        const unsigned short* pe = entb + ((size_t)b * NN + nbase + w * 64) * EE;
#pragma unroll
        for (int i = 0; i < 4; ++i) {
            const unsigned short* pr = pe + (size_t)(i * 16 + l15) * EE + kgrp * 8;
#pragma unroll
            for (int kk = 0; kk < 4; ++kk)
                a[i][kk] = *(const short8*)(pr + kk * 32);
        }
    }

    float rm3[4][4], rm2[4][4];
#pragma unroll
    for (int i = 0; i < 4; ++i)
#pragma unroll
        for (int r = 0; r < 4; ++r) { rm3[i][r] = 3.0e38f; rm2[i][r] = 3.0e38f; }

    const char* s3 = (const char*)f3b + ((size_t)b * FF + fbase) * 256;
    const char* s2 = (const char*)f2b + ((size_t)b * FF + fbase) * 256;
    const float* c3 = Csp + b * FF + fbase;
    const float* c2 = Cpo + b * FF + fbase;

    stage_tile(s3, b3, w, lane);
    __syncthreads();

    for (int ft = 0; ft < 8; ++ft) {
        stage_tile(s2 + (size_t)ft * 32768, b2, w, lane);      // in flight
        compute_tile(b3, c3 + ft * 128, a, l15, kgrp, lane, rm3);
        __syncthreads();                                        // drains, b2 ready
        if (ft < 7) stage_tile(s3 + (size_t)(ft + 1) * 32768, b3, w, lane);
        compute_tile(b2, c2 + ft * 128, a, l15, kgrp, lane, rm2);
        __syncthreads();                                        // b3 ready
    }

    // lane-group min-reduce, write partial min-distances
    float* p0 = pm + (((size_t)fs * 2 + 0) * BB + b) * NN + nbase + w * 64;
    float* p1 = pm + (((size_t)fs * 2 + 1) * BB + b) * NN + nbase + w * 64;
#pragma unroll
    for (int i = 0; i < 4; ++i)
#pragma unroll
        for (int r = 0; r < 4; ++r) {
            float vs = rm3[i][r], vp = rm2[i][r];
#pragma unroll
            for (int o = 1; o < 16; o <<= 1) {
                vs = fminf(vs, __shfl_xor(vs, o, 64));
                vp = fminf(vp, __shfl_xor(vp, o, 64));
            }
            if (l15 == 0) {
                int row = i * 16 + kgrp * 4 + r;
                p0[row] = vs;
                p1[row] = vp;
            }
        }
}

// ---------------------------------------------------------------------------
// Combine: min over the 2 F-split partials, add ||ent||^2, exp, entity mask.
// ---------------------------------------------------------------------------
__global__ __launch_bounds__(512) void combine(
    const float* __restrict__ pm, const float* __restrict__ enorm,
    const int* __restrict__ nbe, float* __restrict__ out)
{
    int idx = blockIdx.x * 512 + threadIdx.x;   // over 2*B*N
    int br  = idx >> 15;
    int rem = idx & 32767;
    int b   = rem >> 12;
    int n   = rem & 4095;
    float d0 = pm[(((size_t)0 + br) * BB + b) * NN + n];
    float d1 = pm[(((size_t)2 + br) * BB + b) * NN + n];
    float d  = fminf(d0, d1);
    bool valid = n < nbe[b];
    out[idx] = valid ? __expf(-0.5f * (d + enorm[(size_t)b * NN + n])) : 0.f;
}

// ---------------------------------------------------------------------------
// Workspace layout (bytes):
//   [0,      4MB)   fact2 bf16 (swizzled)
//   [4MB,    8MB)   fact3 bf16 (swizzled)
//   [8MB,   16MB)   ent bf16 (linear)
//   [16MB,        +64KB)   C_sp
//   [16MB+64K,    +64KB)   C_po
//   [16MB+128K,  +128KB)   ent_norm
//   [16MB+256K,    +1MB)   pm partial mins [fs][branch][B][N]
// ---------------------------------------------------------------------------
extern "C" void kernel_launch(void* const* d_in, const int* in_sizes, int n_in,
                              void* d_out, int out_size, void* d_ws, size_t ws_size,
                              hipStream_t stream) {
    const float* rel  = (const float*)d_in[0];
    const float* arg1 = (const float*)d_in[1];
    const float* arg2 = (const float*)d_in[2];
    const float* f1   = (const float*)d_in[3];
    const float* f2   = (const float*)d_in[4];
    const float* f3   = (const float*)d_in[5];
    const float* ent  = (const float*)d_in[6];
    const int*   nbf  = (const int*)d_in[7];
    const int*   nbe  = (const int*)d_in[8];

    char* ws = (char*)d_ws;
    unsigned short* f2b  = (unsigned short*)(ws);
    unsigned short* f3b  = (unsigned short*)(ws + (4u << 20));
    unsigned short* entb = (unsigned short*)(ws + (8u << 20));
    float* Csp   = (float*)(ws + (16u << 20));
    float* Cpo   = (float*)(ws + (16u << 20) + 65536);
    float* enorm = (float*)(ws + (16u << 20) + 131072);
    float* pm    = (float*)(ws + (16u << 20) + 262144);
    float* out = (float*)d_out;

    hipLaunchKernelGGL(prep_all, dim3(NFB + NEB), dim3(256), 0, stream,
                       rel, arg1, arg2, f1, f2, f3, ent, nbf,
                       f2b, f3b, entb, Csp, Cpo, enorm);
    hipLaunchKernelGGL(kb_main, dim3(512), dim3(128), 0, stream,
                       entb, f2b, f3b, Csp, Cpo, pm);
    hipLaunchKernelGGL(combine, dim3(128), dim3(512), 0, stream,
                       pm, enorm, nbe, out);
}